// Round 12
// baseline (34.997 us; speedup 1.0000x reference)
//
#include <hip/hip_runtime.h>
#include <hip/hip_bf16.h>
#include <math.h>

// Problem constants: N=4, E=64, L=512, D=768
#define PN 4
#define PE 64
#define PL 512
#define PD 768
#define PK2 (2 * PD)        // 1536
#define PM (PN * PE)        // 256 rows

#define EG 16               // entities per pool block (compute density!)
#define DCW 64              // d-columns per pool block (1 f32 per lane)
#define NDC (PD / DCW)      // 12 d-chunks
#define NPOOLB (PN * (PE / EG) * NDC)   // 192 pool blocks
#define NCVT 288            // W-convert blocks (288*512*8 = PD*PK2)
#define NXCD 8

using bf16x8 = __attribute__((ext_vector_type(8))) short;
using f32x4  = __attribute__((ext_vector_type(4))) float;

static __device__ __forceinline__ unsigned short f2bf(float x) {
    unsigned int u = __float_as_uint(x);
    unsigned int r = (u + 0x7FFFu + ((u >> 16) & 1u)) >> 16;   // RNE
    return (unsigned short)r;
}

// ---------------------------------------------------------------------------
// pool_v7: compute-dense pooling. 192 pool blocks + 288 W-convert, 512 thr.
// Pool block = (n, e-group of 16, d-chunk of 64). 8 waves; wave w owns
// l in [w*64, w*64+64) -> all of L covered in-block (no global partials).
// Lane owns ONE d column. Masks: 16x 64-bit ballot -> SGPR (32 SGPRs).
// Per l-iter: 1 global load + 16 x {2 SALU bit/cselect, 3 VALU} = 48 VALU
// (96 cy VALU-pipe) per load -> latency hidden even at 2 waves/SIMD.
// cand = mval * v  (mval in {1.0,0.0} from SALU) == reference mask*doc elem
// EXACTLY (masked-out -> 0 candidate, so no has_zero fixup needed).
// Cross-wave reduce via 64 KB LDS; writes Pb bf16 [256][1536] (max | mean).
// ---------------------------------------------------------------------------
__global__ __launch_bounds__(512) void pool_v7(
    const float* __restrict__ doc,    // [N][L][D]
    const float* __restrict__ map,    // [N][E][L]
    const float* __restrict__ lens,   // [N][E]
    const float* __restrict__ W,      // [768][1536]
    unsigned short* __restrict__ Pb,  // [256][1536] bf16
    unsigned short* __restrict__ Wb)  // [768][1536] bf16
{
    const int bid = blockIdx.x;
    const int tid = threadIdx.x;

    if (bid >= NPOOLB) {
        // ---- W conversion blocks ----
        const size_t i = ((size_t)(bid - NPOOLB) * 512 + tid) * 8;
        const float4 a = *reinterpret_cast<const float4*>(W + i);
        const float4 c = *reinterpret_cast<const float4*>(W + i + 4);
        union { unsigned short s[8]; uint4 v; } r;
        r.s[0] = f2bf(a.x); r.s[1] = f2bf(a.y); r.s[2] = f2bf(a.z); r.s[3] = f2bf(a.w);
        r.s[4] = f2bf(c.x); r.s[5] = f2bf(c.y); r.s[6] = f2bf(c.z); r.s[7] = f2bf(c.w);
        *reinterpret_cast<uint4*>(Wb + i) = r.v;
        return;
    }

    __shared__ float lmax[8][EG][64];   // 32 KB
    __shared__ float lsum[8][EG][64];   // 32 KB

    const int dc   = bid % NDC;          // 0..11
    const int rest = bid / NDC;          // 0..15
    const int eg   = rest & 3;           // 4 e-groups
    const int n    = rest >> 2;          // 0..3
    const int e0   = eg * EG;
    const int d0   = dc * DCW;
    const int w    = tid >> 6;
    const int lane = tid & 63;

    // per-wave 64-bit masks for its own l-window (wave-uniform SGPR)
    unsigned long long mk[EG];
    #pragma unroll
    for (int e = 0; e < EG; ++e) {
        const float m = map[((size_t)n * PE + e0 + e) * PL + w * 64 + lane];
        mk[e] = __ballot(m != 0.0f);
    }

    const float* docp = doc + ((size_t)n * PL + w * 64) * PD + d0 + lane;

    float mx[EG], sm[EG];
    #pragma unroll
    for (int e = 0; e < EG; ++e) { mx[e] = -INFINITY; sm[e] = 0.f; }

    #pragma unroll 4
    for (int l = 0; l < 64; ++l) {
        const float v = docp[(size_t)l * PD];
        #pragma unroll
        for (int e = 0; e < EG; ++e) {
            const float mval = ((mk[e] >> l) & 1ull) ? 1.0f : 0.0f;  // s_cselect
            const float cand = mval * v;      // == reference mask*doc elem
            sm[e] += cand;
            mx[e] = fmaxf(mx[e], cand);
        }
    }

    #pragma unroll
    for (int e = 0; e < EG; ++e) {
        lmax[w][e][lane] = mx[e];
        lsum[w][e][lane] = sm[e];
    }
    __syncthreads();

    // 1024 (e,d) slots; 512 threads handle 2 d each (one d-pair per thread)
    const int e  = tid >> 5;             // 0..15
    const int dd = (tid & 31) << 1;      // 0,2,..,62
    const int ne = n * PE + e0 + e;
    const int d  = d0 + dd;

    float m0 = lmax[0][e][dd], m1 = lmax[0][e][dd + 1];
    float s0 = lsum[0][e][dd], s1 = lsum[0][e][dd + 1];
    #pragma unroll
    for (int ww = 1; ww < 8; ++ww) {
        m0 = fmaxf(m0, lmax[ww][e][dd]);
        m1 = fmaxf(m1, lmax[ww][e][dd + 1]);
        s0 += lsum[ww][e][dd];
        s1 += lsum[ww][e][dd + 1];
    }
    const float inv = 1.0f / lens[ne];
    const unsigned int pkm = (unsigned int)f2bf(m0) | ((unsigned int)f2bf(m1) << 16);
    const unsigned int pks = (unsigned int)f2bf(s0 * inv) | ((unsigned int)f2bf(s1 * inv) << 16);
    *reinterpret_cast<unsigned int*>(Pb + (size_t)ne * PK2 + d)      = pkm;
    *reinterpret_cast<unsigned int*>(Pb + (size_t)ne * PK2 + PD + d) = pks;
}

// ---------------------------------------------------------------------------
// gemm_ks2x (unchanged from R11): MFMA bf16 16x16x32, K-split 2, XCD-aware
// tile mapping (XCD owns a 6-wide ct stripe; W slice L2-resident).
// ---------------------------------------------------------------------------
__global__ __launch_bounds__(128) void gemm_ks2x(
    const unsigned short* __restrict__ Pb,  // [256][1536] bf16
    const unsigned short* __restrict__ Wb,  // [768][1536] bf16
    const float* __restrict__ b,            // [768]
    float* __restrict__ out)                // [256][768]
{
    __shared__ f32x4 red[64];

    const int w    = threadIdx.x >> 6;
    const int lane = threadIdx.x & 63;
    const int bid  = blockIdx.x;
    const int xcd  = bid & (NXCD - 1);
    const int idx  = bid >> 3;               // 0..95
    const int ct = xcd * 6 + (idx >> 4);     // 0..47
    const int rt = idx & 15;                 // 0..15
    const int r0 = rt * 16, d0 = ct * 16;

    const int fr = lane & 15;
    const int kg = lane >> 4;
    const int kb = w * (PK2 / 2);            // 768-wide K slice per wave

    const unsigned short* pA = Pb + (size_t)(r0 + fr) * PK2 + kb + kg * 8;
    const unsigned short* pB = Wb + (size_t)(d0 + fr) * PK2 + kb + kg * 8;

    f32x4 acc0 = {0.f, 0.f, 0.f, 0.f};
    f32x4 acc1 = {0.f, 0.f, 0.f, 0.f};
    #pragma unroll
    for (int k0 = 0; k0 < PK2 / 2; k0 += 64) {
        const bf16x8 a0 = *reinterpret_cast<const bf16x8*>(pA + k0);
        const bf16x8 b0 = *reinterpret_cast<const bf16x8*>(pB + k0);
        acc0 = __builtin_amdgcn_mfma_f32_16x16x32_bf16(a0, b0, acc0, 0, 0, 0);
        const bf16x8 a1 = *reinterpret_cast<const bf16x8*>(pA + k0 + 32);
        const bf16x8 b1 = *reinterpret_cast<const bf16x8*>(pB + k0 + 32);
        acc1 = __builtin_amdgcn_mfma_f32_16x16x32_bf16(a1, b1, acc1, 0, 0, 0);
    }
    f32x4 acc = acc0 + acc1;

    if (w == 1) red[lane] = acc;
    __syncthreads();
    if (w == 0) {
        acc += red[lane];
        const int c = d0 + fr;
        const float bias = b[c];
        #pragma unroll
        for (int j = 0; j < 4; ++j)
            out[(size_t)(r0 + kg * 4 + j) * PD + c] = acc[j] + bias;
    }
}

// ===========================================================================
// Fallback: fully fused f32 (R1-proven) -- used only if ws is tiny.
// ===========================================================================
__global__ __launch_bounds__(256) void fused_kernel(
    const float* __restrict__ doc, const float* __restrict__ map,
    const float* __restrict__ lens, const float* __restrict__ W,
    const float* __restrict__ b, float* __restrict__ out)
{
    __shared__ float Prow[PK2];
    const int ne = blockIdx.x, n = ne >> 6, t = threadIdx.x;
    const float* docn = doc + (size_t)n * PL * PD;
    const float* mrow = map + (size_t)ne * PL;
    float mx0=-INFINITY, mx1=-INFINITY, mx2=-INFINITY, s0=0.f, s1=0.f, s2=0.f;
    bool has_zero = false;
    for (int l = 0; l < PL; ++l) {
        const float m = mrow[l];
        if (m != 0.0f) {
            const float* dr = docn + (size_t)l * PD;
            const float a = dr[t], c = dr[t+256], e = dr[t+512];
            mx0=fmaxf(mx0,a); s0+=a; mx1=fmaxf(mx1,c); s1+=c; mx2=fmaxf(mx2,e); s2+=e;
        } else has_zero = true;
    }
    if (has_zero) { mx0=fmaxf(mx0,0.f); mx1=fmaxf(mx1,0.f); mx2=fmaxf(mx2,0.f); }
    const float invlen = 1.0f / lens[ne];
    Prow[t]=mx0; Prow[t+256]=mx1; Prow[t+512]=mx2;
    Prow[PD+t]=s0*invlen; Prow[PD+t+256]=s1*invlen; Prow[PD+t+512]=s2*invlen;
    __syncthreads();
    #pragma unroll
    for (int i = 0; i < 3; ++i) {
        const int d = t + i*256;
        const float* wrow = W + (size_t)d * PK2;
        float acc = 0.f;
        for (int k = 0; k < PK2; k += 4) {
            const float4 w = *reinterpret_cast<const float4*>(&wrow[k]);
            acc += Prow[k]*w.x + Prow[k+1]*w.y + Prow[k+2]*w.z + Prow[k+3]*w.w;
        }
        out[(size_t)ne * PD + d] = acc + b[d];
    }
}

extern "C" void kernel_launch(void* const* d_in, const int* in_sizes, int n_in,
                              void* d_out, int out_size, void* d_ws, size_t ws_size,
                              hipStream_t stream) {
    const float* doc  = (const float*)d_in[0];   // (4,512,768)
    const float* map  = (const float*)d_in[1];   // (4,64,512)
    const float* lens = (const float*)d_in[2];   // (4,64)
    const float* W    = (const float*)d_in[3];   // (768,1536)
    const float* b    = (const float*)d_in[4];   // (768,)
    float* out = (float*)d_out;                  // (4,64,768)

    const size_t pb_bytes = (size_t)PM * PK2 * sizeof(unsigned short);   // 768 KiB
    const size_t wb_bytes = (size_t)PD * PK2 * sizeof(unsigned short);   // 2.25 MiB
    const size_t need     = pb_bytes + wb_bytes;                         // 3 MiB

    if (ws_size >= need) {
        unsigned short* Pb = (unsigned short*)d_ws;
        unsigned short* Wb = (unsigned short*)((char*)d_ws + pb_bytes);
        pool_v7<<<dim3(NPOOLB + NCVT), dim3(512), 0, stream>>>(
            doc, map, lens, W, Pb, Wb);
        gemm_ks2x<<<dim3((PM / 16) * (PD / 16)), dim3(128), 0, stream>>>(Pb, Wb, b, out);
    } else {
        fused_kernel<<<dim3(PM), dim3(256), 0, stream>>>(doc, map, lens, W, b, out);
    }
}